// Round 1
// baseline (331.659 us; speedup 1.0000x reference)
//
#include <hip/hip_runtime.h>
#include <hip/hip_bf16.h>

// Problem constants
constexpr int BB  = 4;     // batch
constexpr int CC  = 256;   // channels
constexpr int CQ  = 64;    // q/k channels
constexpr int NN  = 4096;  // H*W

typedef __attribute__((ext_vector_type(8))) short bf16x8;  // 8 bf16 (4 VGPRs)
typedef __attribute__((ext_vector_type(4))) float f32x4;   // MFMA accumulator

__device__ __forceinline__ short f2bf(float f) {
    unsigned u = __float_as_uint(f);
    unsigned r = u + 0x7fffu + ((u >> 16) & 1u);   // round-to-nearest-even
    return (short)(r >> 16);
}

// ---------------------------------------------------------------------------
// Kernel 1: QKV projection.
//   x: [B][C][N] fp32.  Outputs:
//   Qt: [B][N][64] bf16   (row i = q[:, i])   -> MFMA A-fragment friendly
//   Kt: [B][N][64] bf16   (row j = k[:, j])   -> MFMA B-fragment friendly
//   Vm: [B][256][N] bf16  (channel-major)     -> MFMA B-fragment friendly for PV
// grid: (N/512, 48, B), block 256.  blockIdx.y picks 8 output channels
// (0..63 -> Q, 64..127 -> K, 128..383 -> V). Each thread computes 2 n's.
// ---------------------------------------------------------------------------
__global__ void proj_kernel(const float* __restrict__ x,
                            const float* __restrict__ Wq, const float* __restrict__ bq,
                            const float* __restrict__ Wk, const float* __restrict__ bk,
                            const float* __restrict__ Wv, const float* __restrict__ bv,
                            short* __restrict__ Qt, short* __restrict__ Kt,
                            short* __restrict__ Vm) {
    const int b  = blockIdx.z;
    const int o0 = blockIdx.y * 8;                 // first of 8 output channels
    const int n0 = blockIdx.x * 512 + threadIdx.x; // first n
    const int n1 = n0 + 256;

    const float* W; const float* bias;
    if (o0 < 64)       { W = Wq + o0 * CC;         bias = bq + o0; }
    else if (o0 < 128) { W = Wk + (o0 - 64) * CC;  bias = bk + (o0 - 64); }
    else               { W = Wv + (o0 - 128) * CC; bias = bv + (o0 - 128); }

    const float* xb = x + (size_t)b * CC * NN;

    float acc0[8], acc1[8];
#pragma unroll
    for (int i = 0; i < 8; ++i) { acc0[i] = bias[i]; acc1[i] = bias[i]; }

#pragma unroll 4
    for (int c = 0; c < CC; ++c) {
        float x0 = xb[(size_t)c * NN + n0];
        float x1 = xb[(size_t)c * NN + n1];
#pragma unroll
        for (int oo = 0; oo < 8; ++oo) {
            float w = W[oo * CC + c];              // uniform -> scalar load
            acc0[oo] += w * x0;
            acc1[oo] += w * x1;
        }
    }

    if (o0 < 128) {
        short* base = (o0 < 64) ? (Qt + ((size_t)b * NN) * 64 + o0)
                                : (Kt + ((size_t)b * NN) * 64 + (o0 - 64));
        bf16x8 p0, p1;
#pragma unroll
        for (int oo = 0; oo < 8; ++oo) { p0[oo] = f2bf(acc0[oo]); p1[oo] = f2bf(acc1[oo]); }
        *(bf16x8*)(base + (size_t)n0 * 64) = p0;
        *(bf16x8*)(base + (size_t)n1 * 64) = p1;
    } else {
        short* vb = Vm + (size_t)b * CC * NN;
        int c0 = o0 - 128;
#pragma unroll
        for (int oo = 0; oo < 8; ++oo) {
            vb[(size_t)(c0 + oo) * NN + n0] = f2bf(acc0[oo]);
            vb[(size_t)(c0 + oo) * NN + n1] = f2bf(acc1[oo]);
        }
    }
}

// ---------------------------------------------------------------------------
// Kernel 2: flash attention + residual epilogue.
// grid: (B, N/64).  block 256 = 4 waves; wave w owns q-rows qt*64+w*16 .. +15.
// Waves are fully independent (no __syncthreads). Online softmax state per
// row lives in the row's 16-lane group.
// MFMA 16x16x32 bf16:
//   A frag: lane l -> row (l&15), k = (l>>4)*8 + e
//   B frag: lane l -> col (l&15), k = (l>>4)*8 + e
//   C/D   : lane l -> col (l&15), row = (l>>4)*4 + reg
// ---------------------------------------------------------------------------
__global__ __launch_bounds__(256) void flash_kernel(
        const short* __restrict__ Qt, const short* __restrict__ Kt,
        const short* __restrict__ Vm,
        const float* __restrict__ x, const float* __restrict__ weightp,
        float* __restrict__ out) {
    const int b    = blockIdx.x;
    const int qt   = blockIdx.y;
    const int wave = threadIdx.x >> 6;
    const int lane = threadIdx.x & 63;
    const int l15  = lane & 15;
    const int g    = lane >> 4;

    const int qbase = qt * 64 + wave * 16;

    const short* Qb = Qt + (size_t)b * NN * 64;
    const short* Kb = Kt + (size_t)b * NN * 64;
    const short* Vb = Vm + (size_t)b * CC * NN;

    // Q fragments (k-chunks 0..31, 32..63)
    bf16x8 qf0 = *(const bf16x8*)(Qb + (size_t)(qbase + l15) * 64 + 0  + g * 8);
    bf16x8 qf1 = *(const bf16x8*)(Qb + (size_t)(qbase + l15) * 64 + 32 + g * 8);

    float m[4], lsum[4];
#pragma unroll
    for (int r = 0; r < 4; ++r) { m[r] = -1e30f; lsum[r] = 0.0f; }
    f32x4 oacc[16];
#pragma unroll
    for (int ch = 0; ch < 16; ++ch) oacc[ch] = (f32x4){0.f, 0.f, 0.f, 0.f};

    __shared__ short plds[4][16][72];              // +8 pad: 2-way banks only
    short (*pl)[72] = plds[wave];

    for (int kt = 0; kt < NN / 64; ++kt) {
        const int kbase = kt * 64;

        // ---- S = Q K^T  (16 x 64 per wave) ----
        f32x4 s[4];
#pragma unroll
        for (int jt = 0; jt < 4; ++jt) {
            const short* kr = Kb + (size_t)(kbase + jt * 16 + l15) * 64 + g * 8;
            bf16x8 kf0 = *(const bf16x8*)(kr);
            bf16x8 kf1 = *(const bf16x8*)(kr + 32);
            f32x4 a = (f32x4){0.f, 0.f, 0.f, 0.f};
            a = __builtin_amdgcn_mfma_f32_16x16x32_bf16(qf0, kf0, a, 0, 0, 0);
            a = __builtin_amdgcn_mfma_f32_16x16x32_bf16(qf1, kf1, a, 0, 0, 0);
            s[jt] = a;
        }

        // ---- row max over the 64 keys (16-lane group butterfly) ----
        float scale[4];
#pragma unroll
        for (int r = 0; r < 4; ++r) {
            float v = fmaxf(fmaxf(s[0][r], s[1][r]), fmaxf(s[2][r], s[3][r]));
            v = fmaxf(v, __shfl_xor(v, 1));
            v = fmaxf(v, __shfl_xor(v, 2));
            v = fmaxf(v, __shfl_xor(v, 4));
            v = fmaxf(v, __shfl_xor(v, 8));
            float mn = fmaxf(m[r], v);
            scale[r] = __expf(m[r] - mn);
            m[r] = mn;
        }

        // ---- P = exp(S - m), row sums, online-state update ----
#pragma unroll
        for (int jt = 0; jt < 4; ++jt)
#pragma unroll
            for (int r = 0; r < 4; ++r)
                s[jt][r] = __expf(s[jt][r] - m[r]);

#pragma unroll
        for (int r = 0; r < 4; ++r) {
            float v = s[0][r] + s[1][r] + s[2][r] + s[3][r];
            v += __shfl_xor(v, 1);
            v += __shfl_xor(v, 2);
            v += __shfl_xor(v, 4);
            v += __shfl_xor(v, 8);
            lsum[r] = lsum[r] * scale[r] + v;
        }

        // ---- rescale O ----
#pragma unroll
        for (int ch = 0; ch < 16; ++ch) {
#pragma unroll
            for (int r = 0; r < 4; ++r) oacc[ch][r] *= scale[r];
        }

        // ---- P -> LDS (S layout) -> A-fragment layout ----
#pragma unroll
        for (int jt = 0; jt < 4; ++jt)
#pragma unroll
            for (int r = 0; r < 4; ++r)
                pl[g * 4 + r][jt * 16 + l15] = f2bf(s[jt][r]);

        bf16x8 pf0 = *(const bf16x8*)&pl[l15][0  + g * 8];
        bf16x8 pf1 = *(const bf16x8*)&pl[l15][32 + g * 8];

        // ---- O += P V  (16 x 256 per wave) ----
#pragma unroll
        for (int ch = 0; ch < 16; ++ch) {
            const short* vr = Vb + (size_t)(ch * 16 + l15) * NN + kbase + g * 8;
            bf16x8 vf0 = *(const bf16x8*)(vr);
            bf16x8 vf1 = *(const bf16x8*)(vr + 32);
            oacc[ch] = __builtin_amdgcn_mfma_f32_16x16x32_bf16(pf0, vf0, oacc[ch], 0, 0, 0);
            oacc[ch] = __builtin_amdgcn_mfma_f32_16x16x32_bf16(pf1, vf1, oacc[ch], 0, 0, 0);
        }
    }

    // ---- epilogue: out = weight * O / lsum + x ----
    const float wgt = weightp[0];
    float rinv[4];
#pragma unroll
    for (int r = 0; r < 4; ++r) rinv[r] = wgt / lsum[r];

    const int qrow0 = qbase + g * 4;               // rows for regs r=0..3
    const float* xb = x + (size_t)b * CC * NN;
    float* ob = out + (size_t)b * CC * NN;
#pragma unroll
    for (int ch = 0; ch < 16; ++ch) {
        int c = ch * 16 + l15;
        size_t base = (size_t)c * NN + qrow0;
        float4 xv = *(const float4*)(xb + base);
        float4 ov;
        ov.x = oacc[ch][0] * rinv[0] + xv.x;
        ov.y = oacc[ch][1] * rinv[1] + xv.y;
        ov.z = oacc[ch][2] * rinv[2] + xv.z;
        ov.w = oacc[ch][3] * rinv[3] + xv.w;
        *(float4*)(ob + base) = ov;
    }
}

extern "C" void kernel_launch(void* const* d_in, const int* in_sizes, int n_in,
                              void* d_out, int out_size, void* d_ws, size_t ws_size,
                              hipStream_t stream) {
    const float* feat = (const float*)d_in[0];
    const float* Wq   = (const float*)d_in[1];
    const float* bq   = (const float*)d_in[2];
    const float* Wk   = (const float*)d_in[3];
    const float* bk   = (const float*)d_in[4];
    const float* Wv   = (const float*)d_in[5];
    const float* bv   = (const float*)d_in[6];
    const float* wgt  = (const float*)d_in[7];
    float* out = (float*)d_out;

    short* Qt = (short*)d_ws;                       // [B][N][64]
    short* Kt = Qt + (size_t)BB * NN * CQ;          // [B][N][64]
    short* Vm = Kt + (size_t)BB * NN * CQ;          // [B][256][N]

    proj_kernel<<<dim3(NN / 512, 48, BB), 256, 0, stream>>>(
        feat, Wq, bq, Wk, bk, Wv, bv, Qt, Kt, Vm);

    flash_kernel<<<dim3(BB, NN / 64), 256, 0, stream>>>(
        Qt, Kt, Vm, feat, wgt, out);
}